// Round 10
// baseline (246.541 us; speedup 1.0000x reference)
//
#include <hip/hip_runtime.h>

#define NK3 30  // 3*K columns per node
#define NKP 15  // float2 pairs per row

__device__ __forceinline__ float hw_log2(float a) { return __builtin_amdgcn_logf(a); }
__device__ __forceinline__ float hw_exp2(float a) { return __builtin_amdgcn_exp2f(a); }
__device__ __forceinline__ float hw_rcp(float a)  { return __builtin_amdgcn_rcpf(a); }

// v += dpp(v): full-rate VALU cross-lane add (NOT a DS op like __shfl_xor).
template <int CTRL>
__device__ __forceinline__ float dpp_add(float v) {
    int s = __builtin_amdgcn_update_dpp(0, __float_as_int(v), CTRL, 0xF, 0xF, true);
    return v + __int_as_float(s);
}
// Reduction ladder within each 16-lane group: after these 4 steps every lane
// of the group holds the group sum. quad_perm[1,0,3,2]=0xB1, [2,3,0,1]=0x4E,
// ROW_HALF_MIRROR=0x141, ROW_MIRROR=0x140.
__device__ __forceinline__ float group16_sum(float v) {
    v = dpp_add<0xB1>(v);
    v = dpp_add<0x4E>(v);
    v = dpp_add<0x141>(v);
    v = dpp_add<0x140>(v);
    return v;
}

// Math: e_nj = exp(x_n + gumbel_nj) = exp2(x_n*log2e) * rcp(-log2 u_nj) * (1/ln2)
//       [1/ln2 cancels in the probs ratio]
// denom'_j = sum_n exp2(xe_n)*rcp(w_nj);  out = exp2(xe)*max_j(r_j * rcp(denom'_j)).

// ---------------- K0: zero the workspace ----------------
__global__ __launch_bounds__(256) void k0_zero(float4* __restrict__ ws, int count4)
{
    const int i = blockIdx.x * 256 + threadIdx.x;
    if (i < count4) ws[i] = make_float4(0.f, 0.f, 0.f, 0.f);
}

// ---------------- K1: row-per-lane + 16-lane DPP tree + group atomics ----------------
// 64 nodes per wave, node = base+lane (N is a 64-multiple). Each lane loads its
// row (15 float2, all live -> loads stay materialized, proven round 9). Per
// distinct segment in the window (wave-uniform loop, avg 1.25): mask, 4-step
// DPP tree per column (120 v_add_f32_dpp), then 30 atomics from lane 0 of each
// 16-lane group (static register indices -> no scratch).
__global__ __launch_bounds__(256) void k1_accumulate(
    const float* __restrict__ x, const float* __restrict__ uniforms,
    const int* __restrict__ ptr, float* __restrict__ wsum, int N, int B)
{
    const int wid  = (blockIdx.x << 2) + (threadIdx.x >> 6);
    const int lane = threadIdx.x & 63;
    const int base = wid << 6;  // 64 nodes / wave
    if (base >= N) return;

    const int n  = base + lane;
    const int nv = (n < N) ? n : (N - 1);   // defensive; N%64==0 here
    const bool valid = (n < N);

    // per-lane segment via binary search (ptr is L1/L2-hot)
    int lo = 0, hi = B;
    while (hi - lo > 1) { int mid = (lo + hi) >> 1; if (ptr[mid] <= nv) lo = mid; else hi = mid; }
    const int seg = lo;

    // load row + compute r_j = exp2(xe) * rcp(-log2 u_j); all 30 live at once
    const float2* row = reinterpret_cast<const float2*>(uniforms + (size_t)nv * NK3);
    float2 u[NKP];
#pragma unroll
    for (int k = 0; k < NKP; ++k) u[k] = row[k];
    const float E = hw_exp2(x[nv] * 1.44269504f);

    float r[NK3];
#pragma unroll
    for (int k = 0; k < NKP; ++k) {
        r[2 * k]     = E * hw_rcp(-hw_log2(u[k].x));
        r[2 * k + 1] = E * hw_rcp(-hw_log2(u[k].y));
    }

    // distinct segments in this window (seg monotone in lane)
    const int s_lo = __shfl(seg, 0, 64);
    const int s_hi = __shfl(seg, 63, 64);

    for (int s = s_lo; s <= s_hi; ++s) {   // wave-uniform, usually 1 iter
        const bool mine = valid && (seg == s);
        float v[NK3];
#pragma unroll
        for (int j = 0; j < NK3; ++j) v[j] = mine ? r[j] : 0.0f;
#pragma unroll
        for (int j = 0; j < NK3; ++j) v[j] = group16_sum(v[j]);
        // r[0] > 0 always for contributing lanes -> v[0] > 0 iff group touched s
        if ((lane & 15) == 0 && v[0] > 0.0f) {
#pragma unroll
            for (int j = 0; j < NK3; ++j)
                atomicAdd(&wsum[(size_t)s * NK3 + j], v[j]);
        }
    }
}

// ---------------- K3: out[n] = exp2(xe) * max_j (r_j * rcp(den_j)) ----------------
// 256 nodes per wave (4 chunks of 64), row-per-lane; rcp applied inline to the
// 30 loaded denominators (no separate k2 pass).
__global__ __launch_bounds__(256) void k3_output(
    const float* __restrict__ x, const float* __restrict__ uniforms,
    const int* __restrict__ ptr, const float* __restrict__ den,
    float* __restrict__ out, int N, int B)
{
    const int wid  = (blockIdx.x << 2) + (threadIdx.x >> 6);
    const int lane = threadIdx.x & 63;
    const int base = wid << 8;  // 256 nodes / wave
    if (base >= N) return;

    const int n0 = base + lane;
    int lo = 0, hi = B;
    while (hi - lo > 1) { int mid = (lo + hi) >> 1; if (ptr[mid] <= n0) lo = mid; else hi = mid; }
    int seg = lo;

    for (int c = 0; c < 4; ++c) {
        const int n = base + (c << 6) + lane;
        if (n >= N) return;
        while (n >= ptr[seg + 1]) ++seg;  // monotone advance, L1-hot

        float l[NK3];
#pragma unroll
        for (int j = 0; j < NK3; ++j) l[j] = hw_rcp(den[seg * NK3 + j]);

        const float2* row = reinterpret_cast<const float2*>(uniforms + (size_t)n * NK3);
        float mx = 0.0f;
#pragma unroll
        for (int k = 0; k < NKP; ++k) {
            const float2 u = row[k];
            const float r0 = hw_rcp(-hw_log2(u.x));
            const float r1 = hw_rcp(-hw_log2(u.y));
            mx = fmaxf(mx, fmaxf(r0 * l[2 * k], r1 * l[2 * k + 1]));
        }
        out[n] = hw_exp2(x[n] * 1.44269504f) * mx;
    }
}

// ---------------- Fallback: single kernel (if ws too small) ----------------
__global__ __launch_bounds__(256) void gnn_fallback(
    const float* __restrict__ x, const float* __restrict__ uniforms,
    const int* __restrict__ ptr, float* __restrict__ out)
{
    const int wave = threadIdx.x >> 6;
    const int lane = threadIdx.x & 63;
    const int g = (blockIdx.x << 2) + wave;
    const int start = ptr[g];
    const int end   = ptr[g + 1];
    if (end <= start) return;

    float acc[NK3];
#pragma unroll
    for (int j = 0; j < NK3; ++j) acc[j] = 0.0f;
    const int iters = (end - start + 63) >> 6;

    for (int it = 0; it < iters; ++it) {
        const int n = start + (it << 6) + lane;
        if (n < end) {
            const float E = hw_exp2(x[n] * 1.44269504f);
            const float2* row = reinterpret_cast<const float2*>(uniforms + (size_t)n * NK3);
#pragma unroll
            for (int k = 0; k < NKP; ++k) {
                float2 u = row[k];
                acc[2 * k]     = fmaf(E, hw_rcp(-hw_log2(u.x)), acc[2 * k]);
                acc[2 * k + 1] = fmaf(E, hw_rcp(-hw_log2(u.y)), acc[2 * k + 1]);
            }
        }
    }
#pragma unroll
    for (int j = 0; j < NK3; ++j) {
        float v = acc[j];
#pragma unroll
        for (int off = 1; off < 64; off <<= 1) v += __shfl_xor(v, off, 64);
        acc[j] = hw_rcp(v);
    }
    for (int it = 0; it < iters; ++it) {
        const int n = start + (it << 6) + lane;
        if (n < end) {
            const float2* row = reinterpret_cast<const float2*>(uniforms + (size_t)n * NK3);
            float mx = 0.0f;
#pragma unroll
            for (int k = 0; k < NKP; ++k) {
                float2 u = row[k];
                const float r0 = hw_rcp(-hw_log2(u.x));
                const float r1 = hw_rcp(-hw_log2(u.y));
                mx = fmaxf(mx, fmaxf(r0 * acc[2 * k], r1 * acc[2 * k + 1]));
            }
            out[n] = hw_exp2(x[n] * 1.44269504f) * mx;
        }
    }
}

extern "C" void kernel_launch(void* const* d_in, const int* in_sizes, int n_in,
                              void* d_out, int out_size, void* d_ws, size_t ws_size,
                              hipStream_t stream) {
    const float* x        = (const float*)d_in[0];
    const float* uniforms = (const float*)d_in[1];
    const int*   ptr      = (const int*)d_in[2];
    float* out = (float*)d_out;

    const int N = in_sizes[0];
    const int B = in_sizes[2] - 1;
    const size_t ws_needed = (size_t)B * NK3 * sizeof(float);

    if (ws_size >= ws_needed && d_ws != nullptr) {
        float* wsum = (float*)d_ws;

        const int cnt  = B * NK3;            // 122880 floats
        const int cnt4 = cnt >> 2;
        const int b0 = (cnt4 + 255) / 256;
        k0_zero<<<b0, 256, 0, stream>>>((float4*)wsum, cnt4);

        const int waves1 = (N + 63) / 64;    // 64 nodes / wave
        const int b1 = (waves1 + 3) / 4;
        k1_accumulate<<<b1, 256, 0, stream>>>(x, uniforms, ptr, wsum, N, B);

        const int b3 = (N + 1023) / 1024;    // 4 waves x 256 nodes
        k3_output<<<b3, 256, 0, stream>>>(x, uniforms, ptr, wsum, out, N, B);
    } else {
        const int blocks = (B + 3) / 4;
        gnn_fallback<<<blocks, 256, 0, stream>>>(x, uniforms, ptr, out);
    }
}

// Round 11
// 76.390 us; speedup vs baseline: 3.2274x; 3.2274x over previous
//
#include <hip/hip_runtime.h>

#define NK3 30  // 3*K columns per node
#define NKP 15  // float2 pairs per row

__device__ __forceinline__ float hw_log2(float a) { return __builtin_amdgcn_logf(a); }
__device__ __forceinline__ float hw_exp2(float a) { return __builtin_amdgcn_exp2f(a); }
__device__ __forceinline__ float hw_rcp(float a)  { return __builtin_amdgcn_rcpf(a); }

// v += dpp(v): full-rate VALU cross-lane add (no DS ops).
template <int CTRL>
__device__ __forceinline__ float dpp_add(float v) {
    int s = __builtin_amdgcn_update_dpp(0, __float_as_int(v), CTRL, 0xF, 0xF, true);
    return v + __int_as_float(s);
}
// 16-lane group sum (every lane gets group sum) — HW-verified round 10.
__device__ __forceinline__ float group16_sum(float v) {
    v = dpp_add<0xB1>(v);    // quad_perm [1,0,3,2]
    v = dpp_add<0x4E>(v);    // quad_perm [2,3,0,1]
    v = dpp_add<0x141>(v);   // ROW_HALF_MIRROR
    v = dpp_add<0x140>(v);   // ROW_MIRROR
    return v;
}
// Full wave64 sum; valid in lanes 48-63 (canonical GCN ladder).
__device__ __forceinline__ float wave64_sum_hi(float v) {
    v = group16_sum(v);
    v = dpp_add<0x142>(v);   // ROW_BCAST15: row r gets row r-1's sum
    v = dpp_add<0x143>(v);   // ROW_BCAST31: rows 2,3 get rows 0+1 sum
    return v;                // lanes 48..63 = total
}

// Math: e_nj = exp(x_n + gumbel_nj) = exp2(x_n*log2e) * rcp(-log2 u_nj) * (1/ln2)
//       [1/ln2 cancels in the probs ratio]
// den_j = sum_n exp2(xe_n)*rcp(w_nj);  out = exp2(xe)*max_j(r_j * rcp(den_j)).

// ---------------- K1: per-window (64-node) column sums. NO atomics, NO ptr. ----------------
__global__ __launch_bounds__(256) void k1_window_sums(
    const float* __restrict__ x, const float* __restrict__ uniforms,
    float* __restrict__ wpart, int N)
{
    const int w    = (blockIdx.x << 2) + (threadIdx.x >> 6);  // window id
    const int lane = threadIdx.x & 63;
    const int base = w << 6;
    if (base >= N) return;

    const int n  = base + lane;
    const int nv = (n < N) ? n : (N - 1);

    const float2* row = reinterpret_cast<const float2*>(uniforms + (size_t)nv * NK3);
    float2 u[NKP];
#pragma unroll
    for (int k = 0; k < NKP; ++k) u[k] = row[k];
    float E = hw_exp2(x[nv] * 1.44269504f);
    E = (n < N) ? E : 0.0f;   // mask tail lanes (defensive; N%64==0 here)

    float r[NK3];
#pragma unroll
    for (int k = 0; k < NKP; ++k) {
        r[2 * k]     = E * hw_rcp(-hw_log2(u[k].x));
        r[2 * k + 1] = E * hw_rcp(-hw_log2(u[k].y));
    }

#pragma unroll
    for (int j = 0; j < NK3; ++j) r[j] = wave64_sum_hi(r[j]);

    if (lane == 63) {
        float* dst = wpart + (size_t)w * NK3;
#pragma unroll
        for (int j = 0; j < NK3; ++j) dst[j] = r[j];
    }
}

// ---------------- K2: per-segment denominators from window partials + edges ----------------
// One wave per segment. lane = h*32 + j (h: even/odd interleave, j<30: column).
// Full windows' partials + direct recompute of edge nodes; shfl_xor(32) combine.
__global__ __launch_bounds__(256) void k2_segment_den(
    const float* __restrict__ x, const float* __restrict__ uniforms,
    const int* __restrict__ ptr, const float* __restrict__ wpart,
    float* __restrict__ den, int B)
{
    const int s = (blockIdx.x << 2) + (threadIdx.x >> 6);
    if (s >= B) return;
    const int lane = threadIdx.x & 63;
    const int h  = lane >> 5;
    const int j  = lane & 31;
    const bool jact = (j < NK3);
    const int jc = jact ? j : 0;

    const int start = ptr[s];
    const int end   = ptr[s + 1];

    const int wlo = (start + 63) >> 6;   // first full window
    const int whi = end >> 6;            // one past last full window
    const int head_end = min(wlo << 6, end);
    const int tail_beg = max(whi << 6, head_end);

    float acc = 0.0f;

    // full windows, interleaved by h
    for (int w = wlo + h; w < whi; w += 2)
        acc += wpart[(size_t)w * NK3 + jc];

    // head edge [start, head_end), interleaved by h
    for (int n = start + h; n < head_end; n += 2) {
        const float E = hw_exp2(x[n] * 1.44269504f);
        const float uv = uniforms[(size_t)n * NK3 + jc];
        acc = fmaf(E, hw_rcp(-hw_log2(uv)), acc);
    }
    // tail edge [tail_beg, end), interleaved by h
    for (int n = tail_beg + h; n < end; n += 2) {
        const float E = hw_exp2(x[n] * 1.44269504f);
        const float uv = uniforms[(size_t)n * NK3 + jc];
        acc = fmaf(E, hw_rcp(-hw_log2(uv)), acc);
    }

    acc += __shfl_xor(acc, 32, 64);      // combine even/odd halves

    if (h == 0 && jact) den[(size_t)s * NK3 + j] = acc;   // coalesced 120B store
}

// ---------------- K3: out[n] = exp2(xe) * max_j (r_j * rcp(den_j)) ----------------
// 256 nodes per wave (4 chunks of 64), row-per-lane (proven fast shape).
__global__ __launch_bounds__(256) void k3_output(
    const float* __restrict__ x, const float* __restrict__ uniforms,
    const int* __restrict__ ptr, const float* __restrict__ den,
    float* __restrict__ out, int N, int B)
{
    const int wid  = (blockIdx.x << 2) + (threadIdx.x >> 6);
    const int lane = threadIdx.x & 63;
    const int base = wid << 8;  // 256 nodes / wave
    if (base >= N) return;

    const int n0 = base + lane;
    int lo = 0, hi = B;
    while (hi - lo > 1) { int mid = (lo + hi) >> 1; if (ptr[mid] <= n0) lo = mid; else hi = mid; }
    int seg = lo;

    for (int c = 0; c < 4; ++c) {
        const int n = base + (c << 6) + lane;
        if (n >= N) return;
        while (n >= ptr[seg + 1]) ++seg;  // monotone advance, L1-hot

        float l[NK3];
#pragma unroll
        for (int j = 0; j < NK3; ++j) l[j] = hw_rcp(den[(size_t)seg * NK3 + j]);

        const float2* row = reinterpret_cast<const float2*>(uniforms + (size_t)n * NK3);
        float mx = 0.0f;
#pragma unroll
        for (int k = 0; k < NKP; ++k) {
            const float2 u = row[k];
            const float r0 = hw_rcp(-hw_log2(u.x));
            const float r1 = hw_rcp(-hw_log2(u.y));
            mx = fmaxf(mx, fmaxf(r0 * l[2 * k], r1 * l[2 * k + 1]));
        }
        out[n] = hw_exp2(x[n] * 1.44269504f) * mx;
    }
}

// ---------------- Fallback: single kernel (if ws too small) ----------------
__global__ __launch_bounds__(256) void gnn_fallback(
    const float* __restrict__ x, const float* __restrict__ uniforms,
    const int* __restrict__ ptr, float* __restrict__ out)
{
    const int wave = threadIdx.x >> 6;
    const int lane = threadIdx.x & 63;
    const int g = (blockIdx.x << 2) + wave;
    const int start = ptr[g];
    const int end   = ptr[g + 1];
    if (end <= start) return;

    float acc[NK3];
#pragma unroll
    for (int j = 0; j < NK3; ++j) acc[j] = 0.0f;
    const int iters = (end - start + 63) >> 6;

    for (int it = 0; it < iters; ++it) {
        const int n = start + (it << 6) + lane;
        if (n < end) {
            const float E = hw_exp2(x[n] * 1.44269504f);
            const float2* row = reinterpret_cast<const float2*>(uniforms + (size_t)n * NK3);
#pragma unroll
            for (int k = 0; k < NKP; ++k) {
                float2 u = row[k];
                acc[2 * k]     = fmaf(E, hw_rcp(-hw_log2(u.x)), acc[2 * k]);
                acc[2 * k + 1] = fmaf(E, hw_rcp(-hw_log2(u.y)), acc[2 * k + 1]);
            }
        }
    }
#pragma unroll
    for (int j = 0; j < NK3; ++j) {
        float v = acc[j];
#pragma unroll
        for (int off = 1; off < 64; off <<= 1) v += __shfl_xor(v, off, 64);
        acc[j] = hw_rcp(v);
    }
    for (int it = 0; it < iters; ++it) {
        const int n = start + (it << 6) + lane;
        if (n < end) {
            const float2* row = reinterpret_cast<const float2*>(uniforms + (size_t)n * NK3);
            float mx = 0.0f;
#pragma unroll
            for (int k = 0; k < NKP; ++k) {
                float2 u = row[k];
                const float r0 = hw_rcp(-hw_log2(u.x));
                const float r1 = hw_rcp(-hw_log2(u.y));
                mx = fmaxf(mx, fmaxf(r0 * acc[2 * k], r1 * acc[2 * k + 1]));
            }
            out[n] = hw_exp2(x[n] * 1.44269504f) * mx;
        }
    }
}

extern "C" void kernel_launch(void* const* d_in, const int* in_sizes, int n_in,
                              void* d_out, int out_size, void* d_ws, size_t ws_size,
                              hipStream_t stream) {
    const float* x        = (const float*)d_in[0];
    const float* uniforms = (const float*)d_in[1];
    const int*   ptr      = (const int*)d_in[2];
    float* out = (float*)d_out;

    const int N = in_sizes[0];
    const int B = in_sizes[2] - 1;
    const int NW = (N + 63) / 64;                     // windows
    const size_t ws_needed = ((size_t)NW + (size_t)B) * NK3 * sizeof(float);

    if (ws_size >= ws_needed && d_ws != nullptr) {
        float* wpart = (float*)d_ws;                  // [NW][30]
        float* den   = wpart + (size_t)NW * NK3;      // [B][30]

        const int b1 = (NW + 3) / 4;                  // 4 windows / block
        k1_window_sums<<<b1, 256, 0, stream>>>(x, uniforms, wpart, N);

        const int b2 = (B + 3) / 4;                   // 4 segments / block
        k2_segment_den<<<b2, 256, 0, stream>>>(x, uniforms, ptr, wpart, den, B);

        const int b3 = (N + 1023) / 1024;             // 4 waves x 256 nodes
        k3_output<<<b3, 256, 0, stream>>>(x, uniforms, ptr, den, out, N, B);
    } else {
        const int blocks = (B + 3) / 4;
        gnn_fallback<<<blocks, 256, 0, stream>>>(x, uniforms, ptr, out);
    }
}

// Round 12
// 70.234 us; speedup vs baseline: 3.5103x; 1.0877x over previous
//
#include <hip/hip_runtime.h>

#define NK3 30  // 3*K columns per node
#define NKP 15  // float2 pairs per row

__device__ __forceinline__ float hw_log2(float a) { return __builtin_amdgcn_logf(a); }
__device__ __forceinline__ float hw_exp2(float a) { return __builtin_amdgcn_exp2f(a); }
__device__ __forceinline__ float hw_rcp(float a)  { return __builtin_amdgcn_rcpf(a); }

// v += dpp(v): full-rate VALU cross-lane add (no DS ops).
template <int CTRL>
__device__ __forceinline__ float dpp_add(float v) {
    int s = __builtin_amdgcn_update_dpp(0, __float_as_int(v), CTRL, 0xF, 0xF, true);
    return v + __int_as_float(s);
}
// 16-lane group sum (every lane gets the group sum) — HW-verified rounds 10/11.
__device__ __forceinline__ float group16_sum(float v) {
    v = dpp_add<0xB1>(v);    // quad_perm [1,0,3,2]
    v = dpp_add<0x4E>(v);    // quad_perm [2,3,0,1]
    v = dpp_add<0x141>(v);   // ROW_HALF_MIRROR
    v = dpp_add<0x140>(v);   // ROW_MIRROR
    return v;
}

// Math: e_nj = exp(x_n + gumbel_nj) = exp2(x_n*log2e) * rcp(-log2 u_nj) * (1/ln2)
//       [1/ln2 cancels in the probs ratio]
// den_j = sum_n exp2(xe_n)*rcp(w_nj);  out = exp2(xe)*max_j(r_j * rcp(den_j)).

// ---------------- K1: 16-node-granularity partial sums. NO atomics, NO ptr. ----------------
// 4 windows of 64 nodes per wave (k3's proven shape -> cross-window MLP).
// Per window: row-per-lane loads, 4-step DPP tree per column, 4 group leaders
// store 30 floats each to wp16[base>>4 .. +3][30].
__global__ __launch_bounds__(256) void k1_window_sums(
    const float* __restrict__ x, const float* __restrict__ uniforms,
    float* __restrict__ wp16, int N)
{
    const int wid  = (blockIdx.x << 2) + (threadIdx.x >> 6);
    const int lane = threadIdx.x & 63;
    const int base0 = wid << 8;   // 256 nodes / wave
    if (base0 >= N) return;

    for (int c = 0; c < 4; ++c) {
        const int base = base0 + (c << 6);
        if (base >= N) return;
        const int n  = base + lane;
        const int nv = (n < N) ? n : (N - 1);

        const float2* row = reinterpret_cast<const float2*>(uniforms + (size_t)nv * NK3);
        float2 u[NKP];
#pragma unroll
        for (int k = 0; k < NKP; ++k) u[k] = row[k];
        float E = hw_exp2(x[nv] * 1.44269504f);
        E = (n < N) ? E : 0.0f;   // defensive; N%64==0 here

        float r[NK3];
#pragma unroll
        for (int k = 0; k < NKP; ++k) {
            r[2 * k]     = E * hw_rcp(-hw_log2(u[k].x));
            r[2 * k + 1] = E * hw_rcp(-hw_log2(u[k].y));
        }

#pragma unroll
        for (int j = 0; j < NK3; ++j) r[j] = group16_sum(r[j]);

        if ((lane & 15) == 0) {   // 4 group leaders store 16-node partials
            float* dst = wp16 + ((size_t)(base >> 4) + (lane >> 4)) * NK3;
#pragma unroll
            for (int j = 0; j < NK3; ++j) dst[j] = r[j];
        }
    }
}

// ---------------- K2: per-segment denominators from 16-node partials + edges ----------------
// One wave per segment. lane = h*32 + j (h: even/odd interleave, j<30: column).
// Window-sum loop is coalesced (30 lanes read 120 contiguous bytes); edge
// recompute now <=15 nodes per side (short serial chains).
__global__ __launch_bounds__(256) void k2_segment_den(
    const float* __restrict__ x, const float* __restrict__ uniforms,
    const int* __restrict__ ptr, const float* __restrict__ wp16,
    float* __restrict__ den, int B)
{
    const int s = (blockIdx.x << 2) + (threadIdx.x >> 6);
    if (s >= B) return;
    const int lane = threadIdx.x & 63;
    const int h  = lane >> 5;
    const int j  = lane & 31;
    const bool jact = (j < NK3);
    const int jc = jact ? j : 0;

    const int start = ptr[s];
    const int end   = ptr[s + 1];

    const int wlo = (start + 15) >> 4;   // first full 16-window
    const int whi = end >> 4;            // one past last full 16-window
    const int head_end = min(wlo << 4, end);
    const int tail_beg = max(whi << 4, head_end);

    float acc = 0.0f;

    // full 16-node windows, interleaved by h (coalesced 120B rows)
    for (int w = wlo + h; w < whi; w += 2)
        acc += wp16[(size_t)w * NK3 + jc];

    // head edge [start, head_end): <=15 nodes
    for (int n = start + h; n < head_end; n += 2) {
        const float E = hw_exp2(x[n] * 1.44269504f);
        const float uv = uniforms[(size_t)n * NK3 + jc];
        acc = fmaf(E, hw_rcp(-hw_log2(uv)), acc);
    }
    // tail edge [tail_beg, end): <=15 nodes
    for (int n = tail_beg + h; n < end; n += 2) {
        const float E = hw_exp2(x[n] * 1.44269504f);
        const float uv = uniforms[(size_t)n * NK3 + jc];
        acc = fmaf(E, hw_rcp(-hw_log2(uv)), acc);
    }

    acc += __shfl_xor(acc, 32, 64);      // combine even/odd halves

    if (h == 0 && jact) den[(size_t)s * NK3 + j] = acc;   // coalesced 120B store
}

// ---------------- K3: out[n] = exp2(xe) * max_j (r_j * rcp(den_j)) ----------------
// 256 nodes per wave (4 chunks of 64), row-per-lane. rcp(den) register-cached
// across chunks, reloaded only when the lane's segment changes.
__global__ __launch_bounds__(256) void k3_output(
    const float* __restrict__ x, const float* __restrict__ uniforms,
    const int* __restrict__ ptr, const float* __restrict__ den,
    float* __restrict__ out, int N, int B)
{
    const int wid  = (blockIdx.x << 2) + (threadIdx.x >> 6);
    const int lane = threadIdx.x & 63;
    const int base = wid << 8;  // 256 nodes / wave
    if (base >= N) return;

    const int n0 = base + lane;
    int lo = 0, hi = B;
    while (hi - lo > 1) { int mid = (lo + hi) >> 1; if (ptr[mid] <= n0) lo = mid; else hi = mid; }
    int seg = lo;

    int cur = -1;
    float l[NK3];

    for (int c = 0; c < 4; ++c) {
        const int n = base + (c << 6) + lane;
        if (n >= N) return;
        while (n >= ptr[seg + 1]) ++seg;  // monotone advance, L1-hot

        if (seg != cur) {                 // reload rcp(den) only on segment change
            cur = seg;
#pragma unroll
            for (int j = 0; j < NK3; ++j) l[j] = hw_rcp(den[(size_t)seg * NK3 + j]);
        }

        const float2* row = reinterpret_cast<const float2*>(uniforms + (size_t)n * NK3);
        float mx = 0.0f;
#pragma unroll
        for (int k = 0; k < NKP; ++k) {
            const float2 u = row[k];
            const float r0 = hw_rcp(-hw_log2(u.x));
            const float r1 = hw_rcp(-hw_log2(u.y));
            mx = fmaxf(mx, fmaxf(r0 * l[2 * k], r1 * l[2 * k + 1]));
        }
        out[n] = hw_exp2(x[n] * 1.44269504f) * mx;
    }
}

// ---------------- Fallback: single kernel (if ws too small) ----------------
__global__ __launch_bounds__(256) void gnn_fallback(
    const float* __restrict__ x, const float* __restrict__ uniforms,
    const int* __restrict__ ptr, float* __restrict__ out)
{
    const int wave = threadIdx.x >> 6;
    const int lane = threadIdx.x & 63;
    const int g = (blockIdx.x << 2) + wave;
    const int start = ptr[g];
    const int end   = ptr[g + 1];
    if (end <= start) return;

    float acc[NK3];
#pragma unroll
    for (int j = 0; j < NK3; ++j) acc[j] = 0.0f;
    const int iters = (end - start + 63) >> 6;

    for (int it = 0; it < iters; ++it) {
        const int n = start + (it << 6) + lane;
        if (n < end) {
            const float E = hw_exp2(x[n] * 1.44269504f);
            const float2* row = reinterpret_cast<const float2*>(uniforms + (size_t)n * NK3);
#pragma unroll
            for (int k = 0; k < NKP; ++k) {
                float2 u = row[k];
                acc[2 * k]     = fmaf(E, hw_rcp(-hw_log2(u.x)), acc[2 * k]);
                acc[2 * k + 1] = fmaf(E, hw_rcp(-hw_log2(u.y)), acc[2 * k + 1]);
            }
        }
    }
#pragma unroll
    for (int j = 0; j < NK3; ++j) {
        float v = acc[j];
#pragma unroll
        for (int off = 1; off < 64; off <<= 1) v += __shfl_xor(v, off, 64);
        acc[j] = hw_rcp(v);
    }
    for (int it = 0; it < iters; ++it) {
        const int n = start + (it << 6) + lane;
        if (n < end) {
            const float2* row = reinterpret_cast<const float2*>(uniforms + (size_t)n * NK3);
            float mx = 0.0f;
#pragma unroll
            for (int k = 0; k < NKP; ++k) {
                float2 u = row[k];
                const float r0 = hw_rcp(-hw_log2(u.x));
                const float r1 = hw_rcp(-hw_log2(u.y));
                mx = fmaxf(mx, fmaxf(r0 * acc[2 * k], r1 * acc[2 * k + 1]));
            }
            out[n] = hw_exp2(x[n] * 1.44269504f) * mx;
        }
    }
}

extern "C" void kernel_launch(void* const* d_in, const int* in_sizes, int n_in,
                              void* d_out, int out_size, void* d_ws, size_t ws_size,
                              hipStream_t stream) {
    const float* x        = (const float*)d_in[0];
    const float* uniforms = (const float*)d_in[1];
    const int*   ptr      = (const int*)d_in[2];
    float* out = (float*)d_out;

    const int N = in_sizes[0];
    const int B = in_sizes[2] - 1;
    const int NW16 = (N + 15) / 16;                   // 16-node windows
    const size_t ws_needed = ((size_t)NW16 + (size_t)B) * NK3 * sizeof(float);

    if (ws_size >= ws_needed && d_ws != nullptr) {
        float* wp16 = (float*)d_ws;                   // [NW16][30]
        float* den  = wp16 + (size_t)NW16 * NK3;      // [B][30]

        const int b1 = (N + 1023) / 1024;             // 4 waves x 256 nodes
        k1_window_sums<<<b1, 256, 0, stream>>>(x, uniforms, wp16, N);

        const int b2 = (B + 3) / 4;                   // 4 segments / block
        k2_segment_den<<<b2, 256, 0, stream>>>(x, uniforms, ptr, wp16, den, B);

        const int b3 = (N + 1023) / 1024;             // 4 waves x 256 nodes
        k3_output<<<b3, 256, 0, stream>>>(x, uniforms, ptr, den, out, N, B);
    } else {
        const int blocks = (B + 3) / 4;
        gnn_fallback<<<blocks, 256, 0, stream>>>(x, uniforms, ptr, out);
    }
}